// Round 1
// baseline (248.095 us; speedup 1.0000x reference)
//
#include <hip/hip_runtime.h>

// R8: barrier-free producer/consumer scan, restructured plumbing.
// Grid: 256 blocks x 192 threads (3 waves), 1 block/CU, 16 rows/block.
// Wave 0 lanes 0..15: consumer (recurrence, software-pipelined register
//   double-buffer across ALL 256 groups, direct global float4 stores).
// Waves 1-2: producers; q=tid-64: pj=q>>3 row (0..15), pk=q&7 phase.
//   x loaded as 8 scalar dwords in the same strided pattern as lstm
//   (no xt LDS exchange). No output staging (no FLUSH/ostg/NOB).
// Tile ring NTB=4, chunks of C=64. Tiles A/B interleaved per element:
//   tile[slot][row*129 + 2*SS] = A, +1 = B. Row stride 129 float4
//   (word stride 516 % 32 == 4 -> 2-way bank aliasing, free).
// Sync: per-wave in-order DS completion => flag written after payload DS
//   ops implies payload visibility. No __syncthreads after init.
// Step math verbatim from R4-R7 (bit-exact):
//   c1 = (p^s1m) >= L1f ; c2 = ((p^f2m) - a3f) >= a4f
//   p  = c2 ? (c1 ? V11 : V01) : (c1 ? L1 : p)

#define C 64
#define NCH 32   // T / C
#define NTB 4    // tile ring depth
#define RS 129   // row stride in float4 (odd -> word stride 516 = 4 mod 32)
#define SLOT (16 * RS)

#define CFENCE() asm volatile("" ::: "memory")

__global__ __launch_bounds__(192) void pc_scan(
    const float* __restrict__ x, const float* __restrict__ p0,
    const float4* __restrict__ lstm4, float* __restrict__ out,
    int B, int T) {
#pragma clang fp contract(off)
  __shared__ float4 tile[NTB][SLOT];  // interleaved (A,B) per element
  __shared__ int stg[NCH][2];         // per-producer-wave stage flags
  __shared__ int scanned;             // chunks fully consumed

  const int tid = threadIdx.x;
  const int b0 = blockIdx.x * 16;
  float4* out4 = reinterpret_cast<float4*>(out);
  (void)B;

  for (int i = tid; i < 2 * NCH; i += 192) ((int*)stg)[i] = 0;
  if (tid == 0) scanned = 0;
  __syncthreads();

  if (tid >= 64) {
    // ======================= PRODUCERS =======================
    const int q = tid - 64;
    const int pj = q >> 3;  // row 0..15 (wave0: 0-7, wave1: 8-15)
    const int pk = q & 7;   // step phase
    const int w = q >> 6;   // producer wave id 0/1
    const bool lead = (q & 63) == 0;

    float4 L00, L01, L02, L03, L04, L05, L06, L07;
    float4 L10, L11, L12, L13, L14, L15, L16, L17;
    float x00, x01, x02, x03, x04, x05, x06, x07;
    float x10, x11, x12, x13, x14, x15, x16, x17;

#define ISSUE(S, CH)                                                    \
  {                                                                     \
    size_t rb = (size_t)(b0 + pj) * T + (size_t)(CH) * C;               \
    const float4* lp = lstm4 + rb + pk;                                 \
    const float* xp = x + rb + pk;                                      \
    L##S##0 = lp[0];  L##S##1 = lp[8];  L##S##2 = lp[16];               \
    L##S##3 = lp[24]; L##S##4 = lp[32]; L##S##5 = lp[40];               \
    L##S##6 = lp[48]; L##S##7 = lp[56];                                 \
    x##S##0 = xp[0];  x##S##1 = xp[8];  x##S##2 = xp[16];               \
    x##S##3 = xp[24]; x##S##4 = xp[32]; x##S##5 = xp[40];               \
    x##S##6 = xp[48]; x##S##7 = xp[56];                                 \
  }

#define STAGE_ELT(LV, XV, TW, OFF)                                      \
  {                                                                     \
    float4 wv = LV; /* (m_lo, m_up, c_lo, c_up) */                      \
    float xv = XV;                                                      \
    float a1 = wv.x * xv, a2 = wv.x * wv.z;                             \
    float L1v = a1 + a2;                                                \
    unsigned s1m = __float_as_uint(wv.x) & 0x80000000u;                 \
    float L1f = __uint_as_float(__float_as_uint(L1v) ^ s1m);            \
    float a3 = wv.y * xv, a4 = wv.y * wv.w;                             \
    unsigned f2m = (__float_as_uint(wv.y) & 0x80000000u) ^ 0x80000000u; \
    float a3f = __uint_as_float(__float_as_uint(a3) ^ f2m);             \
    float a4f = __uint_as_float(__float_as_uint(a4) ^ f2m);             \
    float V01 = a3 + a4;                                                \
    float V11 = (L1v + a3) + a4;                                        \
    (TW)[OFF] = make_float4(__uint_as_float(s1m), L1f,                  \
                            __uint_as_float(f2m), a3f);                 \
    (TW)[(OFF) + 1] = make_float4(a4f, V11, V01, L1v);                  \
  }

#define STAGE(S, BUF)                                                   \
  {                                                                     \
    float4* tw = &tile[BUF][pj * RS + 2 * pk];                          \
    STAGE_ELT(L##S##0, x##S##0, tw, 0)                                  \
    STAGE_ELT(L##S##1, x##S##1, tw, 16)                                 \
    STAGE_ELT(L##S##2, x##S##2, tw, 32)                                 \
    STAGE_ELT(L##S##3, x##S##3, tw, 48)                                 \
    STAGE_ELT(L##S##4, x##S##4, tw, 64)                                 \
    STAGE_ELT(L##S##5, x##S##5, tw, 80)                                 \
    STAGE_ELT(L##S##6, x##S##6, tw, 96)                                 \
    STAGE_ELT(L##S##7, x##S##7, tw, 112)                                \
  }

#define PWAIT(TGT)                                                      \
  while (*(volatile int*)&scanned < (TGT)) __builtin_amdgcn_s_sleep(1); \
  CFENCE();

    ISSUE(0, 0)
    ISSUE(1, 1)

    for (int k = 0; k < NCH; k += 2) {
      // chunk k (set 0): slot k%4 free when chunk k-4 consumed
      PWAIT(k - 3)
      STAGE(0, k & 3)
      CFENCE();
      if (lead) *(volatile int*)&stg[k][w] = 1;
      if (k + 2 < NCH) ISSUE(0, k + 2)
      // chunk k+1 (set 1)
      PWAIT(k - 2)
      STAGE(1, (k + 1) & 3)
      CFENCE();
      if (lead) *(volatile int*)&stg[k + 1][w] = 1;
      if (k + 3 < NCH) ISSUE(1, k + 3)
    }
  } else if (tid < 16) {
    // ======================= CONSUMER (wave 0, lanes 0..15) ===========
    const int row = tid;
    float p = p0[b0 + row];
    float4* op = out4 + (((size_t)(b0 + row) * T) >> 2);
    const float4* base0 = &tile[0][row * RS];
    const float4* slotb = base0;
    const float4* gp;

    float4 rA0E, rA1E, rA2E, rA3E, rA4E, rA5E, rA6E, rA7E;
    float4 rB0E, rB1E, rB2E, rB3E, rB4E, rB5E, rB6E, rB7E;
    float4 rA0O, rA1O, rA2O, rA3O, rA4O, rA5O, rA6O, rA7O;
    float4 rB0O, rB1O, rB2O, rB3O, rB4O, rB5O, rB6O, rB7O;

#define CWAIT(CC)                                                       \
  for (;;) {                                                            \
    int fa = *(volatile int*)&stg[CC][0];                               \
    int fb = *(volatile int*)&stg[CC][1];                               \
    if (fa + fb == 2) break;                                            \
  }                                                                     \
  CFENCE();

#define LOADG(S, P)                                                     \
  rA0##S = (P)[0];  rB0##S = (P)[1];  rA1##S = (P)[2];  rB1##S = (P)[3];\
  rA2##S = (P)[4];  rB2##S = (P)[5];  rA3##S = (P)[6];  rB3##S = (P)[7];\
  rA4##S = (P)[8];  rB4##S = (P)[9];  rA5##S = (P)[10]; rB5##S = (P)[11];\
  rA6##S = (P)[12]; rB6##S = (P)[13]; rA7##S = (P)[14]; rB7##S = (P)[15];

#define RSTEP(S, I, OV)                                                 \
  {                                                                     \
    float4 A = rA##I##S;                                                \
    float4 Bv = rB##I##S;                                               \
    unsigned pu = __float_as_uint(p);                                   \
    float pf = __uint_as_float(pu ^ __float_as_uint(A.x));              \
    bool c1 = pf >= A.y;                                                \
    float pp = __uint_as_float(pu ^ __float_as_uint(A.z));              \
    float qv = pp - A.w;                                                \
    bool c2 = qv >= Bv.x;                                               \
    float i1 = c1 ? Bv.y : Bv.z;                                        \
    float i2 = c1 ? Bv.w : p;                                           \
    p = c2 ? i1 : i2;                                                   \
    OV = p;                                                             \
  }

#define BODY(CUR, NXT, CG, LAST)                                        \
  {                                                                     \
    const int cg_ = (CG);                                               \
    if (!(LAST)) {                                                      \
      int ncg = cg_ + 1;                                                \
      const float4* np;                                                 \
      if ((ncg & 7) == 0) {                                             \
        int nc = ncg >> 3;                                              \
        CWAIT(nc)                                                       \
        slotb = ((nc & 3) == 0) ? base0 : (slotb + SLOT);               \
        np = slotb;                                                     \
      } else {                                                          \
        np = gp + 16;                                                   \
      }                                                                 \
      LOADG(NXT, np)                                                    \
      gp = np;                                                          \
    }                                                                   \
    float4 ov0, ov1;                                                    \
    RSTEP(CUR, 0, ov0.x) RSTEP(CUR, 1, ov0.y)                           \
    RSTEP(CUR, 2, ov0.z) RSTEP(CUR, 3, ov0.w)                           \
    RSTEP(CUR, 4, ov1.x) RSTEP(CUR, 5, ov1.y)                           \
    RSTEP(CUR, 6, ov1.z) RSTEP(CUR, 7, ov1.w)                           \
    op[0] = ov0;                                                        \
    op[1] = ov1;                                                        \
    op += 2;                                                            \
    if (((cg_) & 7) == 7 && row == 0)                                   \
      *(volatile int*)&scanned = (cg_ >> 3) + 1;                        \
  }

    CWAIT(0)
    gp = base0;
    LOADG(E, gp)
    for (int it = 0; it < 127; ++it) {
      BODY(E, O, 2 * it, 0)
      BODY(O, E, 2 * it + 1, 0)
    }
    BODY(E, O, 254, 0)
    BODY(O, E, 255, 1)
  }
}

extern "C" void kernel_launch(void* const* d_in, const int* in_sizes, int n_in,
                              void* d_out, int out_size, void* d_ws, size_t ws_size,
                              hipStream_t stream) {
  const float* x = (const float*)d_in[0];        // (B, T, 1) fp32
  const float* op = (const float*)d_in[1];       // (B, 1, 1) fp32
  const float4* lstm = (const float4*)d_in[2];   // (B, T, 4) fp32
  int B = in_sizes[1];      // 4096
  int T = in_sizes[0] / B;  // 2048
  hipLaunchKernelGGL(pc_scan, dim3(B / 16), dim3(192), 0, stream,
                     x, op, lstm, (float*)d_out, B, T);
}

// Round 2
// 240.057 us; speedup vs baseline: 1.0335x; 1.0335x over previous
//
#include <hip/hip_runtime.h>

// R9: barrier-free producer/consumer scan.
// = R7's proven layouts (tileA/tileB TS=65, ostg+FLUSH output path, NTB=3/NOB=4)
// + R8's two clean wins: (a) producers load x directly from global (no xt LDS
//   round-trip), (b) consumer software-pipelined register double-buffer across
//   all 256 groups (next chunk's CWAIT + group-0 loads overlap current chunk's
//   last group).
// Grid: 256 blocks x 192 threads (3 waves), 1 block/CU, 16 rows/block.
// Wave 0 lanes 0..15: consumer. Waves 1-2: producers (pj=(q>>3)&15, pk=q&7).
// Sync: per-wave in-order DS completion => flag written after payload DS ops
//   implies payload visibility. No __syncthreads after init.
// Step math verbatim from R4-R8 (bit-exact):
//   c1 = (p^s1m) >= L1f ; c2 = ((p^f2m) - a3f) >= a4f
//   p  = c2 ? (c1 ? V11 : V01) : (c1 ? L1 : p)

#define C 64
#define NCH 32   // T / C
#define NTB 3    // tile ring depth
#define NOB 4    // output ring depth
#define TS 65    // tile row stride (float4): word stride 260 % 32 == 4
#define XS 68    // ostg row stride (floats)

#define CFENCE() asm volatile("" ::: "memory")

__global__ __launch_bounds__(192) void pc_scan(
    const float* __restrict__ x, const float* __restrict__ p0,
    const float4* __restrict__ lstm4, float* __restrict__ out,
    int B, int T) {
#pragma clang fp contract(off)
  __shared__ float4 tileA[NTB][16 * TS];  // (s1m, L1f, f2m, a3f)
  __shared__ float4 tileB[NTB][16 * TS];  // (a4f, V11, V01, L1)
  __shared__ float ostg[NOB][16 * XS];    // outputs [row][step]
  __shared__ int stg[NCH][2];             // per-producer-wave stage flags
  __shared__ int scanned;                 // chunks fully consumed

  const int tid = threadIdx.x;
  const int b0 = blockIdx.x * 16;
  float4* out4 = reinterpret_cast<float4*>(out);
  (void)B;

  for (int i = tid; i < 2 * NCH; i += 192) ((int*)stg)[i] = 0;
  if (tid == 0) scanned = 0;
  __syncthreads();

  if (tid >= 64) {
    // ======================= PRODUCERS =======================
    const int q = tid - 64;
    const int pj = (q >> 3) & 15;  // row 0..15
    const int pk = q & 7;          // step phase
    const int w = (tid >> 6) - 1;  // producer wave id 0/1
    const bool lead = (q & 63) == 0;

    float4 L00, L01, L02, L03, L04, L05, L06, L07;
    float4 L10, L11, L12, L13, L14, L15, L16, L17;
    float x00, x01, x02, x03, x04, x05, x06, x07;
    float x10, x11, x12, x13, x14, x15, x16, x17;

#define ISSUE(S, CH)                                                    \
  {                                                                     \
    size_t rb = (size_t)(b0 + pj) * T + (size_t)(CH) * C;               \
    const float4* lp = lstm4 + rb + pk;                                 \
    const float* xp = x + rb + pk;                                      \
    L##S##0 = lp[0];  L##S##1 = lp[8];  L##S##2 = lp[16];               \
    L##S##3 = lp[24]; L##S##4 = lp[32]; L##S##5 = lp[40];               \
    L##S##6 = lp[48]; L##S##7 = lp[56];                                 \
    x##S##0 = xp[0];  x##S##1 = xp[8];  x##S##2 = xp[16];               \
    x##S##3 = xp[24]; x##S##4 = xp[32]; x##S##5 = xp[40];               \
    x##S##6 = xp[48]; x##S##7 = xp[56];                                 \
  }

#define STAGE_ELT(LV, XV, SS, BUF)                                      \
  {                                                                     \
    float4 wv = LV; /* (m_lo, m_up, c_lo, c_up) */                      \
    float xv = XV;                                                      \
    float a1 = wv.x * xv, a2 = wv.x * wv.z;                             \
    float L1v = a1 + a2;                                                \
    unsigned s1m = __float_as_uint(wv.x) & 0x80000000u;                 \
    float L1f = __uint_as_float(__float_as_uint(L1v) ^ s1m);            \
    float a3 = wv.y * xv, a4 = wv.y * wv.w;                             \
    unsigned f2m = (__float_as_uint(wv.y) & 0x80000000u) ^ 0x80000000u; \
    float a3f = __uint_as_float(__float_as_uint(a3) ^ f2m);             \
    float a4f = __uint_as_float(__float_as_uint(a4) ^ f2m);             \
    float V01 = a3 + a4;                                                \
    float V11 = (L1v + a3) + a4;                                        \
    tileA[BUF][pj * TS + (SS)] =                                        \
        make_float4(__uint_as_float(s1m), L1f, __uint_as_float(f2m), a3f); \
    tileB[BUF][pj * TS + (SS)] = make_float4(a4f, V11, V01, L1v);       \
  }

#define STAGE(S, BUF)                                                   \
  {                                                                     \
    STAGE_ELT(L##S##0, x##S##0, pk,      BUF)                           \
    STAGE_ELT(L##S##1, x##S##1, pk + 8,  BUF)                           \
    STAGE_ELT(L##S##2, x##S##2, pk + 16, BUF)                           \
    STAGE_ELT(L##S##3, x##S##3, pk + 24, BUF)                           \
    STAGE_ELT(L##S##4, x##S##4, pk + 32, BUF)                           \
    STAGE_ELT(L##S##5, x##S##5, pk + 40, BUF)                           \
    STAGE_ELT(L##S##6, x##S##6, pk + 48, BUF)                           \
    STAGE_ELT(L##S##7, x##S##7, pk + 56, BUF)                           \
  }

#define FLUSH(CP, OB)                                                   \
  {                                                                     \
    float4 v0 = *(const float4*)&ostg[OB][pj * XS + 8 * pk];            \
    float4 v1 = *(const float4*)&ostg[OB][pj * XS + 8 * pk + 4];        \
    size_t ob = ((size_t)(b0 + pj) * T + (size_t)(CP) * C) >> 2;        \
    out4[ob + 2 * pk] = v0;                                             \
    out4[ob + 2 * pk + 1] = v1;                                         \
  }

#define PWAIT(TGT)                                                      \
  while (*(volatile int*)&scanned < (TGT)) __builtin_amdgcn_s_sleep(1); \
  CFENCE();

    ISSUE(0, 0)
    ISSUE(1, 1)

    for (int k = 0; k < NCH; k += 2) {
      // chunk k (set 0): slot k%3 free once chunk k-3 fully read (scanned>=k-2)
      PWAIT(k - 2)
      STAGE(0, k % NTB)
      CFENCE();
      if (lead) *(volatile int*)&stg[k][w] = 1;
      if (k + 2 < NCH) ISSUE(0, k + 2)
      if (k >= 3) FLUSH(k - 3, (k - 3) & 3)
      // chunk k+1 (set 1)
      PWAIT(k - 1)
      STAGE(1, (k + 1) % NTB)
      CFENCE();
      if (lead) *(volatile int*)&stg[k + 1][w] = 1;
      if (k + 3 < NCH) ISSUE(1, k + 3)
      if (k >= 2) FLUSH(k - 2, (k - 2) & 3)
    }
    // tail: flush chunks NCH-3..NCH-1
    for (int j = NCH - 3; j < NCH; ++j) {
      PWAIT(j + 1)
      FLUSH(j, j & 3)
    }
  } else if (tid < 16) {
    // ======================= CONSUMER (wave 0, lanes 0..15) ===========
    const int row = tid;
    float p = p0[b0 + row];
    const float4* pA;  // next-group tileA read ptr
    const float4* pB;  // next-group tileB read ptr
    float* od;         // current-group ostg write ptr

    float4 rA0E, rA1E, rA2E, rA3E, rA4E, rA5E, rA6E, rA7E;
    float4 rB0E, rB1E, rB2E, rB3E, rB4E, rB5E, rB6E, rB7E;
    float4 rA0O, rA1O, rA2O, rA3O, rA4O, rA5O, rA6O, rA7O;
    float4 rB0O, rB1O, rB2O, rB3O, rB4O, rB5O, rB6O, rB7O;

#define CWAIT(CC)                                                       \
  for (;;) {                                                            \
    int fa = *(volatile int*)&stg[CC][0];                               \
    int fb = *(volatile int*)&stg[CC][1];                               \
    if (fa + fb == 2) break;                                            \
  }                                                                     \
  CFENCE();

#define LOADG(S, PA, PB)                                                \
  rA0##S = (PA)[0]; rA1##S = (PA)[1]; rA2##S = (PA)[2]; rA3##S = (PA)[3];\
  rA4##S = (PA)[4]; rA5##S = (PA)[5]; rA6##S = (PA)[6]; rA7##S = (PA)[7];\
  rB0##S = (PB)[0]; rB1##S = (PB)[1]; rB2##S = (PB)[2]; rB3##S = (PB)[3];\
  rB4##S = (PB)[4]; rB5##S = (PB)[5]; rB6##S = (PB)[6]; rB7##S = (PB)[7];

#define RSTEP(S, I, OV)                                                 \
  {                                                                     \
    float4 A = rA##I##S;                                                \
    float4 Bv = rB##I##S;                                               \
    unsigned pu = __float_as_uint(p);                                   \
    float pf = __uint_as_float(pu ^ __float_as_uint(A.x));              \
    bool c1 = pf >= A.y;                                                \
    float pp = __uint_as_float(pu ^ __float_as_uint(A.z));              \
    float qv = pp - A.w;                                                \
    bool c2 = qv >= Bv.x;                                               \
    float i1 = c1 ? Bv.y : Bv.z;                                        \
    float i2 = c1 ? Bv.w : p;                                           \
    p = c2 ? i1 : i2;                                                   \
    OV = p;                                                             \
  }

#define BODY(CUR, NXT, CG, LAST)                                        \
  {                                                                     \
    const int cg_ = (CG);                                               \
    if (!(LAST)) {                                                      \
      int ncg = cg_ + 1;                                                \
      if ((ncg & 7) == 0) {                                             \
        int nc = ncg >> 3;                                              \
        CWAIT(nc)                                                       \
        pA = &tileA[nc % NTB][row * TS];                                \
        pB = &tileB[nc % NTB][row * TS];                                \
      }                                                                 \
      LOADG(NXT, pA, pB)                                                \
      pA += 8;                                                          \
      pB += 8;                                                          \
    }                                                                   \
    float4 ov0, ov1;                                                    \
    RSTEP(CUR, 0, ov0.x) RSTEP(CUR, 1, ov0.y)                           \
    RSTEP(CUR, 2, ov0.z) RSTEP(CUR, 3, ov0.w)                           \
    RSTEP(CUR, 4, ov1.x) RSTEP(CUR, 5, ov1.y)                           \
    RSTEP(CUR, 6, ov1.z) RSTEP(CUR, 7, ov1.w)                           \
    *(float4*)&od[0] = ov0;                                             \
    *(float4*)&od[4] = ov1;                                             \
    if ((cg_ & 7) == 7) {                                               \
      CFENCE();                                                         \
      if (row == 0) *(volatile int*)&scanned = (cg_ >> 3) + 1;          \
      od = &ostg[((cg_ >> 3) + 1) & 3][row * XS];                       \
    } else {                                                            \
      od += 8;                                                          \
    }                                                                   \
  }

    CWAIT(0)
    pA = &tileA[0][row * TS];
    pB = &tileB[0][row * TS];
    od = &ostg[0][row * XS];
    LOADG(E, pA, pB)
    pA += 8;
    pB += 8;
    for (int it = 0; it < 127; ++it) {
      BODY(E, O, 2 * it, 0)
      BODY(O, E, 2 * it + 1, 0)
    }
    BODY(E, O, 254, 0)
    BODY(O, E, 255, 1)
  }
}

extern "C" void kernel_launch(void* const* d_in, const int* in_sizes, int n_in,
                              void* d_out, int out_size, void* d_ws, size_t ws_size,
                              hipStream_t stream) {
  const float* x = (const float*)d_in[0];        // (B, T, 1) fp32
  const float* op = (const float*)d_in[1];       // (B, 1, 1) fp32
  const float4* lstm = (const float4*)d_in[2];   // (B, T, 4) fp32
  int B = in_sizes[1];      // 4096
  int T = in_sizes[0] / B;  // 2048
  hipLaunchKernelGGL(pc_scan, dim3(B / 16), dim3(192), 0, stream,
                     x, op, lstm, (float*)d_out, B, T);
}